// Round 7
// baseline (159.593 us; speedup 1.0000x reference)
//
#include <hip/hip_runtime.h>
#include <float.h>
#include <stdint.h>

// Forbid FMA contraction: reference (numpy fp32) rounds every mul/add
// separately; a fused (a1+a2)-iw*ih could flip an iou>0.5 decision.
#pragma clang fp contract(off)

#define NEGV   (-1e9f)
#define THRV   (0.05f)
#define MAXDET 100
#define NB     1152        // score buckets
#define BKBASE 31385       // (bits(0.05f) >> 15)
#define SLABSZ 1024        // LDS chunk capacity
#define CHTGT  512         // target chunk size (head of sorted order)
#define TKCAP  1024        // LDS-resident topk candidates; overflow -> global

__device__ __forceinline__ int bktOf(unsigned u) {
  int v = (int)(u >> 15) - BKBASE;          // monotone in float for s > 0
  return v < 0 ? 0 : (v > NB - 1 ? NB - 1 : v);
}

// Bit-exact "(iou > 0.5)" decision. Certain cases via the two-sided window
// (margin 1e-5 >> max rounding error); ambiguous window does the exact
// reference IEEE divide.
__device__ __forceinline__ bool killpair(
    float qx1, float qy1, float qx2, float qy2, float qa,
    float x1, float y1, float x2, float y2, float a)
{
  const float iw = fminf(qx2, x2) - fmaxf(qx1, x1);
  const float ih = fminf(qy2, y2) - fmaxf(qy1, y1);
  if (iw <= 0.f || ih <= 0.f) return false;
  const float inter = iw * ih;
  const float den = fmaxf((qa + a) - inter, 1e-8f);
  const float i2 = inter + inter;
  if (i2 > den * 1.00001f) return true;
  if (i2 < den * 0.99999f) return false;
  return (inter / den) > 0.5f;
}

// suffix-sum of hist[] (descending bucket layout): hist[bk] becomes the count
// of elements in buckets STRICTLY ABOVE bk (= start position of bucket bk,
// bucket NB-1 first). Returns total count. Ends with a barrier.
template<int BT>
__device__ __forceinline__ int suffix_scan(int* hist, int* wtot,
                                           int tid, int lane, int wid) {
  int c0 = 0, c1 = 0, c2 = 0;
  if (tid < NB / 3) {
    c0 = hist[NB - 1 - 3 * tid];
    c1 = hist[NB - 2 - 3 * tid];
    c2 = hist[NB - 3 - 3 * tid];
  }
  const int tsum = c0 + c1 + c2;
  int inc = tsum;
#pragma unroll
  for (int off = 1; off < 64; off <<= 1) {
    const int u = __shfl_up(inc, off, 64);
    if (lane >= off) inc += u;
  }
  if (lane == 63) wtot[wid] = inc;
  __syncthreads();
  int wbase = 0, tot = 0;
#pragma unroll
  for (int w = 0; w < BT / 64; ++w) {
    const int v = wtot[w];
    if (w < wid) wbase += v;
    tot += v;
  }
  const int excl = wbase + inc - tsum;
  if (tid < NB / 3) {
    hist[NB - 1 - 3 * tid] = excl;
    hist[NB - 2 - 3 * tid] = excl + c0;
    hist[NB - 3 - 3 * tid] = excl + c0 + c1;
  }
  __syncthreads();
  return tot;
}

// Batched sorted scan: keep candidate iff no previously-kept box IoU>0.5.
// keys descending (score desc, orig idx asc). Returns nk. Barriers inside.
template<int BT>
__device__ int run_scan(
    const unsigned long long* kL, const unsigned long long* kG, bool useL,
    int cn, const float4* __restrict__ bb4,
    float4* kboxS, float* kscoreS, float* kareaS,
    unsigned long long* wkill, unsigned long long* killby,
    int tid, int lane, int wid)
{
#pragma clang fp contract(off)
  constexpr int NW = BT / 64;
  constexpr int CPW = 64 / NW;            // in-batch columns per wave
  int nk = 0;
  for (int base = 0; base < cn && nk < MAXDET; base += 64) {
    const int nc = min(64, cn - base);
    const bool valid = lane < nc;
    const int p = base + lane;
    unsigned long long key = 0ull;
    if (valid) key = useL ? kL[p] : kG[p];
    const float score = __uint_as_float((unsigned)(key >> 32));
    const int idx = (int)(~(unsigned)key);
    float4 bx = make_float4(0.f, 0.f, 0.f, 0.f);
    if (valid) bx = bb4[idx];
    const float area = (bx.z - bx.x) * (bx.w - bx.y);

    // vs already-kept: wave w checks kept entries w, w+NW, ...
    bool kill = false;
    for (int e = wid; e < nk; e += NW) {
      const float4 q = kboxS[e];
      kill = kill || killpair(q.x, q.y, q.z, q.w, kareaS[e],
                              bx.x, bx.y, bx.z, bx.w, area);
    }
    {
      const unsigned long long bm = __ballot(valid && kill);
      if (lane == 0) wkill[wid] = bm;
    }
    // in-batch 64x64 matrix: wave w computes columns j = CPW*w .. CPW*w+CPW-1
    {
      const int cb = wid * CPW;
#pragma unroll
      for (int jj = 0; jj < CPW; ++jj) {
        const int j = cb + jj;
        if (j < nc) {
          const float jx1 = __int_as_float(__builtin_amdgcn_readlane(__float_as_int(bx.x), j));
          const float jy1 = __int_as_float(__builtin_amdgcn_readlane(__float_as_int(bx.y), j));
          const float jx2 = __int_as_float(__builtin_amdgcn_readlane(__float_as_int(bx.z), j));
          const float jy2 = __int_as_float(__builtin_amdgcn_readlane(__float_as_int(bx.w), j));
          const float ja  = __int_as_float(__builtin_amdgcn_readlane(__float_as_int(area), j));
          const bool kij = valid && killpair(jx1, jy1, jx2, jy2, ja,
                                             bx.x, bx.y, bx.z, bx.w, area);
          const unsigned long long bm = __ballot(kij);
          if (lane == 0) killby[j] = bm;
        }
      }
    }
    __syncthreads();                      // wkill/killby ready

    // serial mask resolution (all threads redundantly; masks via readlane)
    unsigned long long kmask = 0;
#pragma unroll
    for (int w = 0; w < NW; ++w) kmask |= wkill[w];
    unsigned long long alive = ~kmask;
    alive &= (nc >= 64) ? ~0ull : ((1ull << nc) - 1ull);
    const unsigned long long kb = killby[lane];
    for (int j = 0; j < 64; ++j) {
      if ((alive >> j) & 1ull) {
        const unsigned klo = (unsigned)__builtin_amdgcn_readlane((int)(unsigned)kb, j);
        const unsigned khi = (unsigned)__builtin_amdgcn_readlane((int)(unsigned)(kb >> 32), j);
        const unsigned long long km = ((unsigned long long)khi << 32) | klo;
        alive &= ~(km & ((~1ull) << j));  // kill only lower-score (higher j') bits
      }
    }
    // append kept (wave 0 writes; alive/nk uniform across all threads)
    if (wid == 0) {
      const int rank = (int)__popcll(alive & ((1ull << lane) - 1ull));
      if (((alive >> lane) & 1ull) && (nk + rank < MAXDET)) {
        kboxS[nk + rank] = bx;
        kscoreS[nk + rank] = score;
        kareaS[nk + rank] = area;
      }
    }
    nk += min((int)__popcll(alive), MAXDET - nk);
    __syncthreads();                      // kept visible for next batch
  }
  return nk;
}

// ---------------------------------------------------------------------------
// Kernel 0: cls (B,N,C) -> clsT (B,C,N), LDS-tiled, fully coalesced.
// ---------------------------------------------------------------------------
__global__ __launch_bounds__(256, 1) void transpose_kernel(
    const float* __restrict__ cls, float* __restrict__ clsT, int N, int C)
{
  __shared__ float tile[32][33];
  const int b = blockIdx.z;
  const int n0 = blockIdx.x * 32, c0 = blockIdx.y * 32;
  const int tx = threadIdx.x, ty = threadIdx.y;   // 32 x 8
#pragma unroll
  for (int r = ty; r < 32; r += 8) {
    const int n = n0 + r, c = c0 + tx;
    if (n < N && c < C) tile[r][tx] = cls[((size_t)b * N + n) * C + c];
  }
  __syncthreads();
#pragma unroll
  for (int r = ty; r < 32; r += 8) {
    const int c = c0 + r, n = n0 + tx;
    if (n < N && c < C) clsT[((size_t)b * C + c) * N + n] = tile[tx][r];
  }
}

// ---------------------------------------------------------------------------
// Kernel 1: per-(image,class) NMS = radix-SELECT top chunk (~512+) ->
// rank-by-count sort -> batched sorted scan. Slow full-sort fallback for
// pathological inputs (chunk overflow / >chunk candidates needed).
// Also publishes per-image histogram of kept scores for topk.
// ---------------------------------------------------------------------------
template<int BT>
__global__ __launch_bounds__(BT, 1) void nms_kernel(
    const float* __restrict__ boxes, const float* __restrict__ clsT,
    unsigned long long* __restrict__ skg_all,
    float* __restrict__ ksc, float* __restrict__ kbx,
    int* __restrict__ ihist, int N, int C)
{
#pragma clang fp contract(off)
  const int bc = blockIdx.x;
  const int tid = threadIdx.x, lane = tid & 63, wid = tid >> 6;

  const float* ct = clsT + (size_t)bc * N;       // contiguous class column
  const float4* bb4 = (const float4*)(boxes + (size_t)(bc / C) * N * 4);
  unsigned long long* skg = skg_all + (size_t)bc * N;  // slow path only

  __shared__ unsigned long long slab[SLABSZ];
  __shared__ unsigned long long sorted[SLABSZ];
  __shared__ int hist[NB];
  __shared__ int wtot[BT / 64];
  __shared__ float4 kboxS[MAXDET];
  __shared__ float  kscoreS[MAXDET];
  __shared__ float  kareaS[MAXDET];
  __shared__ unsigned long long wkill[BT / 64];
  __shared__ unsigned long long killby[64];
  __shared__ int bkLoS;

  // ---- Phase 0: histogram of alive scores (coalesced read) ----
  for (int i = tid; i < NB; i += BT) hist[i] = 0;
  if (tid == 0) bkLoS = -1;
  __syncthreads();
  for (int i = tid; i < N; i += BT) {
    const float s = ct[i];
    if (s > THRV) atomicAdd(&hist[bktOf(__float_as_uint(s))], 1);
  }
  __syncthreads();

  // ---- Phase 1: suffix scan -> hist[bk] = count above bk ----
  const int cn = suffix_scan<BT>(hist, wtot, tid, lane, wid);

  // ---- Phase 2: chunk select: bkLo = max{bk : count-above >= CHTGT} ----
  for (int bk = tid; bk < NB; bk += BT)
    if (hist[bk] >= CHTGT) atomicMax(&bkLoS, bk);
  __syncthreads();
  const int bkLo = bkLoS;
  const int chunkCnt = (bkLo >= 0) ? hist[bkLo] : cn;   // read BEFORE scatter

  int nk = 0;
  bool slow = (chunkCnt > SLABSZ);
  if (!slow) {
    // scatter chunk (buckets > bkLo) into LDS slab
    for (int i = tid; i < N; i += BT) {
      const float s = ct[i];
      if (s > THRV) {
        const unsigned u = __float_as_uint(s);
        const int bk = bktOf(u);
        if (bk > bkLo) {
          const int pos = atomicAdd(&hist[bk], 1);
          slab[pos] = ((unsigned long long)u << 32) | (unsigned)(~i);
        }
      }
    }
    __syncthreads();
    // rank-by-count sort (keys unique; broadcast LDS reads, no divergence)
    for (int e = tid; e < chunkCnt; e += BT) {
      const unsigned long long k = slab[e];
      int r = 0;
      for (int j = 0; j < chunkCnt; ++j) r += (slab[j] > k) ? 1 : 0;
      sorted[r] = k;
    }
    __syncthreads();
    nk = run_scan<BT>(sorted, skg, true, chunkCnt, bb4,
                      kboxS, kscoreS, kareaS, wkill, killby, tid, lane, wid);
    slow = (nk < MAXDET && chunkCnt < cn);
  }

  if (slow) {
    // ---- full fallback: re-histogram, scatter ALL to global, per-bucket
    // insertion sort, rescan from scratch. Correct for any input. ----
    __syncthreads();
    for (int i = tid; i < NB; i += BT) hist[i] = 0;
    __syncthreads();
    for (int i = tid; i < N; i += BT) {
      const float s = ct[i];
      if (s > THRV) atomicAdd(&hist[bktOf(__float_as_uint(s))], 1);
    }
    __syncthreads();
    suffix_scan<BT>(hist, wtot, tid, lane, wid);
    for (int i = tid; i < N; i += BT) {
      const float s = ct[i];
      if (s > THRV) {
        const unsigned u = __float_as_uint(s);
        const int pos = atomicAdd(&hist[bktOf(u)], 1);
        skg[pos] = ((unsigned long long)u << 32) | (unsigned)(~i);
      }
    }
    __syncthreads();
    for (int bk = tid; bk < NB; bk += BT) {
      const int lo = (bk == NB - 1) ? 0 : hist[bk + 1];
      const int hi = hist[bk];
      for (int x = lo + 1; x < hi; ++x) {
        const unsigned long long v = skg[x];
        int y = x - 1;
        while (y >= lo && skg[y] < v) { skg[y + 1] = skg[y]; --y; }
        skg[y + 1] = v;
      }
    }
    __syncthreads();
    nk = run_scan<BT>(sorted, skg, false, cn, bb4,
                      kboxS, kscoreS, kareaS, wkill, killby, tid, lane, wid);
  }

  // ---- emit + per-image kept-score histogram for topk ----
  float* ko  = ksc + (size_t)bc * MAXDET;
  float* kbo = kbx + (size_t)bc * MAXDET * 4;
  int* ih = ihist + (size_t)(bc / C) * NB;
  for (int e = tid; e < MAXDET; e += BT) {
    if (e < nk) {
      const float4 q = kboxS[e];
      const float s = kscoreS[e];
      ko[e] = s;
      kbo[e * 4 + 0] = q.x; kbo[e * 4 + 1] = q.y;
      kbo[e * 4 + 2] = q.z; kbo[e * 4 + 3] = q.w;
      atomicAdd(&ih[bktOf(__float_as_uint(s))], 1);
    } else {
      ko[e] = NEGV;
      kbo[e * 4 + 0] = 0.f; kbo[e * 4 + 1] = 0.f;
      kbo[e * 4 + 2] = 0.f; kbo[e * 4 + 3] = 0.f;
    }
  }
}

// ---------------------------------------------------------------------------
// Kernel 2: per-image top-100 via radix-select on the precomputed kept-score
// histogram: threshold bucket -> compact ~107 candidates -> rank-by-count.
// Key (score_bits<<32 | ~flat_idx) == lax.top_k (value desc, idx asc).
// ---------------------------------------------------------------------------
template<int BT>
__global__ __launch_bounds__(BT, 1) void topk_kernel(
    const float* __restrict__ ksc, const float* __restrict__ kbx,
    const int* __restrict__ ihist, unsigned long long* __restrict__ gcand_all,
    float* __restrict__ out, int B, int C)
{
  const int b = blockIdx.x;
  const int tid = threadIdx.x, lane = tid & 63, wid = tid >> 6;
  const int T = C * MAXDET;
  const float* s0 = ksc + (size_t)b * T;
  unsigned long long* gc = gcand_all + (size_t)b * T;   // overflow only
  float* ob = out;                              // [B][100][4]
  float* os = out + (size_t)B * MAXDET * 4;     // [B][100]
  float* ol = os + (size_t)B * MAXDET;          // [B][100] labels as float

  __shared__ int hist[NB];
  __shared__ int wtot[BT / 64];
  __shared__ unsigned long long cand[TKCAP];
  __shared__ int tBs, cposS;

  for (int i = tid; i < NB; i += BT) hist[i] = ihist[(size_t)b * NB + i];
  if (tid == 0) { cposS = 0; tBs = 0; }
  __syncthreads();
  suffix_scan<BT>(hist, wtot, tid, lane, wid);
  // threshold bucket: the unique crossing where count-above drops < MAXDET
  for (int bk = tid; bk < NB; bk += BT)
    if (hist[bk] < MAXDET && (bk == 0 || hist[bk - 1] >= MAXDET)) tBs = bk;
  __syncthreads();
  const int t = tBs;
  for (int f = tid; f < T; f += BT) {
    const float s = s0[f];
    if (s > THRV) {
      const unsigned u = __float_as_uint(s);
      if (bktOf(u) >= t) {
        const int p = atomicAdd(&cposS, 1);
        const unsigned long long key =
            ((unsigned long long)u << 32) | (unsigned)(~f);
        if (p < TKCAP) cand[p] = key; else gc[p] = key;
      }
    }
  }
  __syncthreads();
  const int nc = cposS;
  const int nw = min(nc, MAXDET);
  // prefill only the never-written slots (no race with winner writes)
  for (int s2 = nw + tid; s2 < MAXDET; s2 += BT) {
    float* od = ob + ((size_t)b * MAXDET + s2) * 4;
    od[0] = -1.f; od[1] = -1.f; od[2] = -1.f; od[3] = -1.f;
    os[(size_t)b * MAXDET + s2] = -1.f;
    ol[(size_t)b * MAXDET + s2] = -1.f;
  }
  // rank by counting (keys unique -> ranks unique), emit winners
  for (int e = tid; e < nc; e += BT) {
    const unsigned long long k = (e < TKCAP) ? cand[e] : gc[e];
    int rank = 0;
    for (int j = 0; j < nc; ++j) {
      const unsigned long long o = (j < TKCAP) ? cand[j] : gc[j];
      rank += (o > k) ? 1 : 0;
    }
    if (rank < MAXDET) {
      const int f = (int)(~(unsigned)k);
      const float sc = __uint_as_float((unsigned)(k >> 32));
      const float* bp = kbx + ((size_t)b * T + f) * 4;
      float* od = ob + ((size_t)b * MAXDET + rank) * 4;
      od[0] = bp[0]; od[1] = bp[1]; od[2] = bp[2]; od[3] = bp[3];
      os[(size_t)b * MAXDET + rank] = sc;
      ol[(size_t)b * MAXDET + rank] = (float)(f / MAXDET);
    }
  }
}

extern "C" void kernel_launch(void* const* d_in, const int* in_sizes, int n_in,
                              void* d_out, int out_size, void* d_ws, size_t ws_size,
                              hipStream_t stream) {
  const float* boxes = (const float*)d_in[0];  // (B, N, 4) f32
  const float* cls   = (const float*)d_in[1];  // (B, N, C) f32
  const int B = out_size / (MAXDET * 6);       // 4 box + 1 score + 1 label
  const int N = in_sizes[0] / (B * 4);
  const int C = in_sizes[1] / (B * N);

  char* ws = (char*)d_ws;
  unsigned long long* skg = (unsigned long long*)ws;
  ws += (size_t)B * C * N * 8;                               // slow-path slab
  unsigned long long* gcand = (unsigned long long*)ws;
  ws += (size_t)B * C * MAXDET * 8;                          // topk overflow
  float* clsT = (float*)ws; ws += (size_t)B * C * N * 4;     // transposed cls
  float* kbx = (float*)ws;  ws += (size_t)B * C * MAXDET * 16; // kept boxes
  float* ksc = (float*)ws;  ws += (size_t)B * C * MAXDET * 4;  // kept scores
  int* ihist = (int*)ws;                                     // per-image hist

  hipMemsetAsync(ihist, 0, (size_t)B * NB * 4, stream);
  transpose_kernel<<<dim3((N + 31) / 32, (C + 31) / 32, B), dim3(32, 8),
                     0, stream>>>(cls, clsT, N, C);
  nms_kernel<1024><<<dim3(B * C), dim3(1024), 0, stream>>>(
      boxes, clsT, skg, ksc, kbx, ihist, N, C);
  topk_kernel<1024><<<dim3(B), dim3(1024), 0, stream>>>(
      ksc, kbx, ihist, gcand, (float*)d_out, B, C);
}